// Round 3
// baseline (4422.481 us; speedup 1.0000x reference)
//
#include <hip/hip_runtime.h>
#include <stdint.h>

// GNNCell: 2x SAGEConv(lstm) + 2 MLP heads. N=100000, D=16, H=128, fp32 I/O.
// R9 passed (absmax 3.9e-3) at 3322 us; lstm_comb 2x1175 us = 71%.
// Counters: VALU 38.6% > MFMA 24% > HBM 14.6%; occ 21% == 2 waves/SIMD
// (weights live in AGPRs: 128 VGPR + ~128 AGPR per wave -> register-capped,
// occupancy not raisable without evicting Whh from regs).
// R10: (1) v_cvt_pk_bf16_f32 everywhere bf16 packing happens: splitf8
//     (56->24 ops), hs pack (34->12 ops/nt), cvtb8/headgemm store. The
//     split scheme is self-compensating (lo = x-hi exact), rounding-mode
//     safe. (2) 1-deep MFMA/ACT software pipeline inside LSTM_STEP:
//     MFMA0,MFMA1,ACT0,MFMA2,ACT1,MFMA3,ACT2,ACT3 with two named acc
//     sets -> nt0's X gather consumed ~480+cyc after issue (covers L3
//     latency), activation VALU overlaps next tile's MFMAs.
// Precision scheme unchanged: X fp16-hi + i8-lo(2^-15), split-bf16 3-MFMA
// recurrence/X-GEMM/combine, hs bf16 hi/lo planes.

typedef __attribute__((ext_vector_type(8))) short short8_t;
typedef __attribute__((ext_vector_type(4))) float float4_t;
typedef __attribute__((ext_vector_type(4))) unsigned uint4_t;
typedef _Float16 half8_t __attribute__((ext_vector_type(8)));

#define NNODES 100000
#define DNB 16
#define LOSCALE 32768.0f
#define LOINV   3.0517578125e-5f   // 2^-15

__device__ __forceinline__ float fsigf(float x) {
    return __builtin_amdgcn_rcpf(1.f + __expf(-x));
}
__device__ __forceinline__ float ftanhf(float x) {
    return 1.f - 2.f * __builtin_amdgcn_rcpf(1.f + __expf(2.f * x));
}
__device__ __forceinline__ float blo(unsigned u) { return __uint_as_float(u << 16); }
__device__ __forceinline__ float bhi(unsigned u) { return __uint_as_float(u & 0xFFFF0000u); }
// packed f32 pair -> 2x bf16 in one u32 (lo = src0, hi = src1)
__device__ __forceinline__ unsigned cvtpk(float lo, float hi) {
    unsigned r;
    asm("v_cvt_pk_bf16_f32 %0, %1, %2" : "=v"(r) : "v"(lo), "v"(hi));
    return r;
}
// split fp32[8] -> bf16 hi + bf16 lo fragments (compensated GEMM inputs)
__device__ __forceinline__ void splitf8(const float* __restrict__ p, short8_t& hi, short8_t& lo) {
    float4_t a = *(const float4_t*)p;
    float4_t b = *(const float4_t*)(p + 4);
    unsigned h0 = cvtpk(a[0], a[1]), h1 = cvtpk(a[2], a[3]);
    unsigned h2 = cvtpk(b[0], b[1]), h3 = cvtpk(b[2], b[3]);
    unsigned l0 = cvtpk(a[0] - blo(h0), a[1] - bhi(h0));
    unsigned l1 = cvtpk(a[2] - blo(h1), a[3] - bhi(h1));
    unsigned l2 = cvtpk(b[0] - blo(h2), b[1] - bhi(h2));
    unsigned l3 = cvtpk(b[2] - blo(h3), b[3] - bhi(h3));
    union { uint4_t u; short8_t s; } ch, cl;
    ch.u = (uint4_t){h0, h1, h2, h3};
    cl.u = (uint4_t){l0, l1, l2, l3};
    hi = ch.s;
    lo = cl.s;
}
// fp32[8] -> bf16x8 (plain cast, head path)
__device__ __forceinline__ short8_t cvtb8(const float* __restrict__ p) {
    float4_t a = *(const float4_t*)p;
    float4_t b = *(const float4_t*)(p + 4);
    union { uint4_t u; short8_t s; } c;
    c.u = (uint4_t){cvtpk(a[0], a[1]), cvtpk(a[2], a[3]),
                    cvtpk(b[0], b[1]), cvtpk(b[2], b[3])};
    return c.s;
}

// ---------------------------------------------------------------------------
// X = h @ Wih.T + b, split-bf16 3-MFMA (rel ~2^-16), stored fp16-hi + i8-lo.
// Output layout is GATE-INTERLEAVED: element c = g*128+j stored at
// node*512 + j*4 + g, so the lstm gather reads one contiguous 48B run/lane.
// ---------------------------------------------------------------------------
__global__ __launch_bounds__(256) void xgemm_split(
    const float* __restrict__ A, const float* __restrict__ B,
    const float* __restrict__ bias, _Float16* __restrict__ Chi,
    char* __restrict__ Clo)
{
    const int tid  = threadIdx.x;
    const int wave = tid >> 6, lane = tid & 63;
    const int l15  = lane & 15, quad = lane >> 4;
    const int r0   = blockIdx.y * 64 + wave * 16;
    const int c0   = blockIdx.x * 64;

    int arow = r0 + l15;
    if (arow >= NNODES) arow = NNODES - 1;

    float4_t acc[4];
#pragma unroll
    for (int ct = 0; ct < 4; ++ct) acc[ct] = (float4_t){0.f, 0.f, 0.f, 0.f};

#pragma unroll
    for (int kc = 0; kc < 4; ++kc) {
        const int kk = kc * 32 + quad * 8;
        short8_t ah, al;
        splitf8(A + (size_t)arow * 128 + kk, ah, al);
#pragma unroll
        for (int ct = 0; ct < 4; ++ct) {
            short8_t bh, bl;
            splitf8(B + (size_t)(c0 + ct * 16 + l15) * 128 + kk, bh, bl);
            acc[ct] = __builtin_amdgcn_mfma_f32_16x16x32_bf16(ah, bh, acc[ct], 0, 0, 0);
            acc[ct] = __builtin_amdgcn_mfma_f32_16x16x32_bf16(ah, bl, acc[ct], 0, 0, 0);
            acc[ct] = __builtin_amdgcn_mfma_f32_16x16x32_bf16(al, bh, acc[ct], 0, 0, 0);
        }
    }

#pragma unroll
    for (int ct = 0; ct < 4; ++ct) {
        int c = c0 + ct * 16 + l15;
        float bb = bias[c];
        const int jj = c & 127, gg = c >> 7;          // gate-interleaved slot
#pragma unroll
        for (int r = 0; r < 4; ++r) {
            int rowo = r0 + quad * 4 + r;
            if (rowo < NNODES) {
                float v = acc[ct][r] + bb;
                _Float16 hi = (_Float16)v;
                float res = v - (float)hi;
                int q = (int)rintf(res * LOSCALE);
                q = q > 127 ? 127 : (q < -127 ? -127 : q);
                Chi[(size_t)rowo * 512 + jj * 4 + gg] = hi;
                Clo[(size_t)rowo * 512 + jj * 4 + gg] = (char)q;
            }
        }
    }
}

// ---------------------------------------------------------------------------
// Fused 16-step LSTM + combine. Block = 64 nodes, 512 threads (8 waves).
// Wave w owns hidden slice j in [16w, 16w+16) for ALL 4 gates (4 tiles).
// hs in DOUBLE-BUFFERED bf16 hi/lo LDS planes -> ONE barrier per step.
// X gathers (gate-interleaved) issued at step start; 1-deep pipeline:
// MFMA0,MFMA1,ACT0,MFMA2,ACT1,MFMA3,ACT2,ACT3 so nt0's X is consumed
// ~2 MFMA-chains after issue and ACT VALU overlaps later MFMAs.
// nbr staged in LDS [64][17]. hs pack via v_cvt_pk_bf16_f32.
// ---------------------------------------------------------------------------
__global__ __launch_bounds__(512, 2) void lstm_comb(
    const _Float16* __restrict__ Xhi, const char* __restrict__ Xlo,
    const int* __restrict__ nbr, const float* __restrict__ Whh,
    const float* hin, const float* __restrict__ Ws,
    const float* __restrict__ Wn, const float* __restrict__ bs,
    const float* __restrict__ bn, float* hout)
{
    __shared__ short hsAhi[64 * 136], hsAlo[64 * 136];
    __shared__ short hsBhi[64 * 136], hsBlo[64 * 136];
    __shared__ int   nbrs[64 * 17];

    const int tid  = threadIdx.x;
    const int wave = tid >> 6, lane = tid & 63;
    const int l15  = lane & 15, quad = lane >> 4;
    const int n0   = blockIdx.x * 64;
    const int jb   = wave * 16;
    const int xoff = jb * 4 + quad * 16;   // gate-interleaved lane offset

    for (int i = tid; i < 64 * 136 / 2; i += 512) {
        ((unsigned*)hsAhi)[i] = 0;
        ((unsigned*)hsAlo)[i] = 0;
    }
    for (int i = tid; i < 64 * DNB; i += 512) {
        int node = n0 + (i >> 4);
        if (node >= NNODES) node = NNODES - 1;
        nbrs[(i >> 4) * 17 + (i & 15)] = nbr[node * DNB + (i & 15)];
    }

    // Whh split fragments: 4 gates x 4 k-chunks x (hi,lo) = 32 frags
    short8_t whi[4][4], wlo[4][4];
#pragma unroll
    for (int g = 0; g < 4; ++g)
#pragma unroll
        for (int kc = 0; kc < 4; ++kc)
            splitf8(Whh + (size_t)(g * 128 + jb + l15) * 128 + kc * 32 + quad * 8,
                    whi[g][kc], wlo[g][kc]);

    float cs[4][4], nh[4][4];
#pragma unroll
    for (int a = 0; a < 4; ++a)
#pragma unroll
        for (int b = 0; b < 4; ++b) { cs[a][b] = 0.f; nh[a][b] = 0.f; }

    __syncthreads();

// hi value (g,r) lives at vector slot r*4+g; lo byte g of word r.
#define XV(nt, r, g)                                                                \
    ((float)(((r) * 4 + (g)) < 8 ? xh0[nt][(r) * 4 + (g)] : xh1[nt][(r) * 4 + (g) - 8]) \
     + (float)((signed char)(xl4[nt][(r)] >> ((g) * 8))) * LOINV)

#define GEMM_NT(nt, AC, rdHi, rdLo)                                                 \
    {                                                                               \
        short8_t hfh[4], hfl[4];                                                    \
        _Pragma("unroll")                                                           \
        for (int kc = 0; kc < 4; ++kc) {                                            \
            hfh[kc] = *(const short8_t*)&(rdHi)[((nt) * 16 + l15) * 136 + kc * 32 + quad * 8]; \
            hfl[kc] = *(const short8_t*)&(rdLo)[((nt) * 16 + l15) * 136 + kc * 32 + quad * 8]; \
        }                                                                           \
        _Pragma("unroll")                                                           \
        for (int g = 0; g < 4; ++g) {                                               \
            float4_t a = (float4_t){0.f, 0.f, 0.f, 0.f};                            \
            _Pragma("unroll")                                                       \
            for (int kc = 0; kc < 4; ++kc) {                                        \
                a = __builtin_amdgcn_mfma_f32_16x16x32_bf16(whi[g][kc], hfh[kc], a, 0, 0, 0); \
                a = __builtin_amdgcn_mfma_f32_16x16x32_bf16(whi[g][kc], hfl[kc], a, 0, 0, 0); \
                a = __builtin_amdgcn_mfma_f32_16x16x32_bf16(wlo[g][kc], hfh[kc], a, 0, 0, 0); \
            }                                                                       \
            AC[g] = a;                                                              \
        }                                                                           \
    }

#define ACTV(nt, AC)                                                                \
    _Pragma("unroll")                                                               \
    for (int r = 0; r < 4; ++r) {                                                   \
        float iv = AC[0][r] + XV(nt, r, 0);                                         \
        float fv = AC[1][r] + XV(nt, r, 1);                                         \
        float gv = AC[2][r] + XV(nt, r, 2);                                         \
        float ov = AC[3][r] + XV(nt, r, 3);                                         \
        float c = fsigf(fv) * cs[nt][r] + fsigf(iv) * ftanhf(gv);                   \
        cs[nt][r] = c;                                                              \
        nh[nt][r] = fsigf(ov) * ftanhf(c);                                          \
    }

#define LSTM_STEP(rdHi, rdLo, wrHi, wrLo, T)                                        \
    {                                                                               \
        half8_t xh0[4], xh1[4]; uint4_t xl4[4];                                     \
        _Pragma("unroll")                                                           \
        for (int nt = 0; nt < 4; ++nt) {                                            \
            int gi = nbrs[(nt * 16 + l15) * 17 + (T)];                              \
            size_t xb = (size_t)gi * 512 + xoff;                                    \
            xh0[nt] = *(const half8_t*)(Xhi + xb);                                  \
            xh1[nt] = *(const half8_t*)(Xhi + xb + 8);                              \
            xl4[nt] = *(const uint4_t*)(Xlo + xb);                                  \
        }                                                                           \
        float4_t acA[4], acB[4];                                                    \
        GEMM_NT(0, acA, rdHi, rdLo)                                                 \
        GEMM_NT(1, acB, rdHi, rdLo)                                                 \
        ACTV(0, acA)                                                                \
        GEMM_NT(2, acA, rdHi, rdLo)                                                 \
        ACTV(1, acB)                                                                \
        GEMM_NT(3, acB, rdHi, rdLo)                                                 \
        ACTV(2, acA)                                                                \
        ACTV(3, acB)                                                                \
        _Pragma("unroll")                                                           \
        for (int nt = 0; nt < 4; ++nt) {                                            \
            unsigned p0 = cvtpk(nh[nt][0], nh[nt][1]);                              \
            unsigned p1 = cvtpk(nh[nt][2], nh[nt][3]);                              \
            unsigned q0 = cvtpk(nh[nt][0] - blo(p0), nh[nt][1] - bhi(p0));          \
            unsigned q1 = cvtpk(nh[nt][2] - blo(p1), nh[nt][3] - bhi(p1));          \
            uint2 ph; ph.x = p0; ph.y = p1;                                         \
            uint2 pl; pl.x = q0; pl.y = q1;                                         \
            const int o = (nt * 16 + l15) * 136 + jb + quad * 4;                    \
            *(uint2*)&(wrHi)[o] = ph;                                               \
            *(uint2*)&(wrLo)[o] = pl;                                               \
        }                                                                           \
        __syncthreads();                                                            \
    }

    for (int tp = 0; tp < 8; ++tp) {
        LSTM_STEP(hsAhi, hsAlo, hsBhi, hsBlo, 2 * tp);      // even t: read A write B
        LSTM_STEP(hsBhi, hsBlo, hsAhi, hsAlo, 2 * tp + 1);  // odd  t: read B write A
    }
#undef LSTM_STEP
#undef ACTV
#undef GEMM_NT
#undef XV
    // t=15 (odd) wrote A planes -> h_neigh lives in hsA.

    // ---- fused combine: h' = relu(hin@Ws.T + hn@Wn.T + bs + bn) ----
    // wave -> node group (wave&3, 16 nodes) x ct half (wave>>2, 4 tiles).
    const int ng = wave & 3, ch = wave >> 2;
    const int nodeA = n0 + ng * 16 + l15;
    const int nclA  = nodeA < NNODES ? nodeA : NNODES - 1;
    short8_t ahh[4], ahl[4], anh[4], anl[4];
#pragma unroll
    for (int kc = 0; kc < 4; ++kc) {
        splitf8(hin + (size_t)nclA * 128 + kc * 32 + quad * 8, ahh[kc], ahl[kc]);
        anh[kc] = *(const short8_t*)&hsAhi[(ng * 16 + l15) * 136 + kc * 32 + quad * 8];
        anl[kc] = *(const short8_t*)&hsAlo[(ng * 16 + l15) * 136 + kc * 32 + quad * 8];
    }
    __syncthreads();   // all hin reads done before any in-place store

#pragma unroll
    for (int ct = 0; ct < 4; ++ct) {
        const int ctg = ch * 4 + ct;
        float4_t acc = (float4_t){0.f, 0.f, 0.f, 0.f};
#pragma unroll
        for (int kc = 0; kc < 4; ++kc) {
            const int kk = kc * 32 + quad * 8;
            short8_t bh, bl;
            splitf8(Ws + (size_t)(ctg * 16 + l15) * 128 + kk, bh, bl);
            acc = __builtin_amdgcn_mfma_f32_16x16x32_bf16(ahh[kc], bh, acc, 0, 0, 0);
            acc = __builtin_amdgcn_mfma_f32_16x16x32_bf16(ahh[kc], bl, acc, 0, 0, 0);
            acc = __builtin_amdgcn_mfma_f32_16x16x32_bf16(ahl[kc], bh, acc, 0, 0, 0);
            splitf8(Wn + (size_t)(ctg * 16 + l15) * 128 + kk, bh, bl);
            acc = __builtin_amdgcn_mfma_f32_16x16x32_bf16(anh[kc], bh, acc, 0, 0, 0);
            acc = __builtin_amdgcn_mfma_f32_16x16x32_bf16(anh[kc], bl, acc, 0, 0, 0);
            acc = __builtin_amdgcn_mfma_f32_16x16x32_bf16(anl[kc], bh, acc, 0, 0, 0);
        }
        const int c = ctg * 16 + l15;
        const float bb = bs[c] + bn[c];
#pragma unroll
        for (int r = 0; r < 4; ++r) {
            int rowo = n0 + ng * 16 + quad * 4 + r;
            if (rowo < NNODES) {
                float v = acc[r] + bb;
                hout[(size_t)rowo * 128 + c] = v > 0.f ? v : 0.f;
            }
        }
    }
}

// ---------------------------------------------------------------------------
// Stacked head layer: rows [0,N) use (Bc,bc), rows [N,2N) use (Bn,bn).
// afmt=1: A fp32 N rows (both halves read same rows); afmt=0: A bf16 2N rows.
// ---------------------------------------------------------------------------
__global__ __launch_bounds__(256) void headgemm_b(
    const float* __restrict__ A32, const short* __restrict__ A16,
    const float* __restrict__ Bc, const float* __restrict__ Bn,
    const float* __restrict__ bc, const float* __restrict__ bn,
    short* __restrict__ C, int afmt)
{
    const int tid  = threadIdx.x;
    const int wave = tid >> 6, lane = tid & 63;
    const int l15  = lane & 15, quad = lane >> 4;
    const int r0   = blockIdx.x * 64 + wave * 16;
    const int c0   = blockIdx.y * 64;

    const float* Bw = (r0 < NNODES) ? Bc : Bn;
    const float* bw = (r0 < NNODES) ? bc : bn;
    int arow = r0 + l15;
    if (afmt && arow >= NNODES) arow -= NNODES;

    float4_t acc[4];
#pragma unroll
    for (int ct = 0; ct < 4; ++ct) acc[ct] = (float4_t){0.f, 0.f, 0.f, 0.f};

#pragma unroll
    for (int kc = 0; kc < 4; ++kc) {
        const int kk = kc * 32 + quad * 8;
        short8_t af = afmt ? cvtb8(A32 + (size_t)arow * 128 + kk)
                           : *(const short8_t*)(A16 + (size_t)arow * 128 + kk);
#pragma unroll
        for (int ct = 0; ct < 4; ++ct) {
            short8_t bf = cvtb8(Bw + (size_t)(c0 + ct * 16 + l15) * 128 + kk);
            acc[ct] = __builtin_amdgcn_mfma_f32_16x16x32_bf16(af, bf, acc[ct], 0, 0, 0);
        }
    }

#pragma unroll
    for (int ct = 0; ct < 4; ++ct) {
        int c = c0 + ct * 16 + l15;
        float bb = bw[c];
        float v0 = acc[ct][0] + bb; v0 = v0 > 0.f ? v0 : 0.f;
        float v1 = acc[ct][1] + bb; v1 = v1 > 0.f ? v1 : 0.f;
        float v2 = acc[ct][2] + bb; v2 = v2 > 0.f ? v2 : 0.f;
        float v3 = acc[ct][3] + bb; v3 = v3 > 0.f ? v3 : 0.f;
        unsigned p01 = cvtpk(v0, v1), p23 = cvtpk(v2, v3);
        int rb = r0 + quad * 4;
        C[(size_t)(rb + 0) * 128 + c] = (short)(p01 & 0xffff);
        C[(size_t)(rb + 1) * 128 + c] = (short)(p01 >> 16);
        C[(size_t)(rb + 2) * 128 + c] = (short)(p23 & 0xffff);
        C[(size_t)(rb + 3) * 128 + c] = (short)(p23 >> 16);
    }
}

// out[n*C+c] = x[n,:].W[c,:] + b[c]   (C = 10 or 1), bf16 acts, fp32 out.
__global__ __launch_bounds__(256) void final_b(
    const short* __restrict__ xin, const float* __restrict__ W,
    const float* __restrict__ b, float* __restrict__ out, int C)
{
    int idx = blockIdx.x * blockDim.x + threadIdx.x;
    if (idx >= NNODES * C) return;
    int n = idx / C, c = idx - n * C;
    const short* xr = xin + (size_t)n * 128;
    const float* wr = W + (size_t)c * 128;
    float acc = b[c];
#pragma unroll
    for (int i = 0; i < 16; ++i) {
        uint4 xv = *(const uint4*)(xr + i * 8);
        const float* w = wr + i * 8;
        acc += blo(xv.x) * w[0] + bhi(xv.x) * w[1]
             + blo(xv.y) * w[2] + bhi(xv.y) * w[3]
             + blo(xv.z) * w[4] + bhi(xv.z) * w[5]
             + blo(xv.w) * w[6] + bhi(xv.w) * w[7];
    }
    out[idx] = acc;
}

// ===========================================================================
extern "C" void kernel_launch(void* const* d_in, const int* in_sizes, int n_in,
                              void* d_out, int out_size, void* d_ws, size_t ws_size,
                              hipStream_t stream)
{
    const float* h0     = (const float*)d_in[0];
    const int*   nbr    = (const int*)d_in[1];
    const float* Wih    = (const float*)d_in[2];   // [2,512,128]
    const float* Whh    = (const float*)d_in[3];   // [2,512,128]
    const float* lb     = (const float*)d_in[4];   // [2,512]
    const float* Wself  = (const float*)d_in[5];   // [2,128,128]
    const float* bself  = (const float*)d_in[6];
    const float* Wneigh = (const float*)d_in[7];
    const float* bneigh = (const float*)d_in[8];
    const float* clsW   = (const float*)d_in[9];   // [5,128,128]
    const float* clsb   = (const float*)d_in[10];
    const float* clsoW  = (const float*)d_in[11];  // [10,128]
    const float* clsob  = (const float*)d_in[12];
    const float* cnfW   = (const float*)d_in[13];
    const float* cnfb   = (const float*)d_in[14];
    const float* cnfoW  = (const float*)d_in[15];  // [1,128]
    const float* cnfob  = (const float*)d_in[16];

    char* ws = (char*)d_ws;
    _Float16* Xhi = (_Float16*)ws;                 // [0, 102.4M)
    char*     Xlo = ws + 102400000;                // [102.4M, 153.6M)
    short*    actA = (short*)ws;                   // phase B: [0, 51.2M)
    short*    actB = (short*)(ws + 51200000);      // phase B: [51.2M, 102.4M)

    float* out = (float*)d_out;
    float* oC  = out;                   // [N,10]
    float* hO  = out + 1000000;         // [N,128] output 1; h1/h2 live here
    float* oL  = out + 13800000;        // [N,1]

    dim3 gx(8, 1563);    // xgemm: cols fast (L2 write-merge), M=100000, NC=512
    dim3 gl(1563);       // lstm_comb, 512 thr
    dim3 gh(3125, 2);    // heads: M=200000, NC=128, 256 thr

    // ---- layer 1: h1 -> d_out h slot ----
    xgemm_split<<<gx, dim3(256), 0, stream>>>(h0, Wih, lb, Xhi, Xlo);
    lstm_comb<<<gl, dim3(512), 0, stream>>>(Xhi, Xlo, nbr, Whh, h0,
                                            Wself, Wneigh, bself, bneigh, hO);
    // ---- layer 2: h2 -> same slot, in-place ----
    xgemm_split<<<gx, dim3(256), 0, stream>>>(hO, Wih + 65536, lb + 512, Xhi, Xlo);
    lstm_comb<<<gl, dim3(512), 0, stream>>>(Xhi, Xlo, nbr, Whh + 65536, hO,
                                            Wself + 16384, Wneigh + 16384,
                                            bself + 128, bneigh + 128, hO);

    // ---- heads: stacked cls (rows<N) / cnf (rows>=N) ----
    headgemm_b<<<gh, dim3(256), 0, stream>>>(hO, nullptr, clsW, cnfW, clsb, cnfb, actA, 1);
    short* cur = actA; short* nxt = actB;
    for (int i = 1; i < 5; ++i) {
        headgemm_b<<<gh, dim3(256), 0, stream>>>(nullptr, cur, clsW + i * 16384, cnfW + i * 16384,
                                                 clsb + i * 128, cnfb + i * 128, nxt, 0);
        short* tv = cur; cur = nxt; nxt = tv;
    }
    final_b<<<dim3((NNODES * 10 + 255) / 256), dim3(256), 0, stream>>>(cur, clsoW, clsob, oC, 10);
    final_b<<<dim3((NNODES + 255) / 256), dim3(256), 0, stream>>>(cur + (size_t)NNODES * 128,
                                                                  cnfoW, cnfob, oL, 1);
}

// Round 4
// 3565.830 us; speedup vs baseline: 1.2402x; 1.2402x over previous
//
#include <hip/hip_runtime.h>
#include <stdint.h>

// GNNCell: 2x SAGEConv(lstm) + 2 MLP heads. N=100000, D=16, H=128, fp32 I/O.
// R9  passed 3322 us (lstm 2x1175): VALU 38.6 > MFMA 24 > HBM 14.6, occ 21%
//     (2 waves/SIMD, weights in regs: ~256/wave -> register-capped).
// R10 REGRESSED 4422 us: 1-deep MFMA/ACT pipeline (acA+acB) pushed live set
//     past 256 regs -> scratch spills (WRITE_SIZE 78MB->1.07GB, FETCH
//     1.26->2.78GB). Lesson: zero register headroom in lstm_comb.
// R11: revert pipeline to R9's sequential GEMM->ACT per nt (single ac[4]);
//     KEEP the cvtpk (v_cvt_pk_bf16_f32) conversions from R10 - they cut
//     VALU cycles (420 vs 454 us) and are numerically identical (absmax
//     unchanged). No other changes: clean attribution.
// Precision scheme unchanged: X fp16-hi + i8-lo(2^-15), split-bf16 3-MFMA
// recurrence/X-GEMM/combine, hs bf16 hi/lo planes.

typedef __attribute__((ext_vector_type(8))) short short8_t;
typedef __attribute__((ext_vector_type(4))) float float4_t;
typedef __attribute__((ext_vector_type(4))) unsigned uint4_t;
typedef _Float16 half8_t __attribute__((ext_vector_type(8)));

#define NNODES 100000
#define DNB 16
#define LOSCALE 32768.0f
#define LOINV   3.0517578125e-5f   // 2^-15

__device__ __forceinline__ float fsigf(float x) {
    return __builtin_amdgcn_rcpf(1.f + __expf(-x));
}
__device__ __forceinline__ float ftanhf(float x) {
    return 1.f - 2.f * __builtin_amdgcn_rcpf(1.f + __expf(2.f * x));
}
__device__ __forceinline__ float blo(unsigned u) { return __uint_as_float(u << 16); }
__device__ __forceinline__ float bhi(unsigned u) { return __uint_as_float(u & 0xFFFF0000u); }
// packed f32 pair -> 2x bf16 in one u32 (lo = src0, hi = src1)
__device__ __forceinline__ unsigned cvtpk(float lo, float hi) {
    unsigned r;
    asm("v_cvt_pk_bf16_f32 %0, %1, %2" : "=v"(r) : "v"(lo), "v"(hi));
    return r;
}
// split fp32[8] -> bf16 hi + bf16 lo fragments (compensated GEMM inputs)
__device__ __forceinline__ void splitf8(const float* __restrict__ p, short8_t& hi, short8_t& lo) {
    float4_t a = *(const float4_t*)p;
    float4_t b = *(const float4_t*)(p + 4);
    unsigned h0 = cvtpk(a[0], a[1]), h1 = cvtpk(a[2], a[3]);
    unsigned h2 = cvtpk(b[0], b[1]), h3 = cvtpk(b[2], b[3]);
    unsigned l0 = cvtpk(a[0] - blo(h0), a[1] - bhi(h0));
    unsigned l1 = cvtpk(a[2] - blo(h1), a[3] - bhi(h1));
    unsigned l2 = cvtpk(b[0] - blo(h2), b[1] - bhi(h2));
    unsigned l3 = cvtpk(b[2] - blo(h3), b[3] - bhi(h3));
    union { uint4_t u; short8_t s; } ch, cl;
    ch.u = (uint4_t){h0, h1, h2, h3};
    cl.u = (uint4_t){l0, l1, l2, l3};
    hi = ch.s;
    lo = cl.s;
}
// fp32[8] -> bf16x8 (plain cast, head path)
__device__ __forceinline__ short8_t cvtb8(const float* __restrict__ p) {
    float4_t a = *(const float4_t*)p;
    float4_t b = *(const float4_t*)(p + 4);
    union { uint4_t u; short8_t s; } c;
    c.u = (uint4_t){cvtpk(a[0], a[1]), cvtpk(a[2], a[3]),
                    cvtpk(b[0], b[1]), cvtpk(b[2], b[3])};
    return c.s;
}

// ---------------------------------------------------------------------------
// X = h @ Wih.T + b, split-bf16 3-MFMA (rel ~2^-16), stored fp16-hi + i8-lo.
// Output layout is GATE-INTERLEAVED: element c = g*128+j stored at
// node*512 + j*4 + g, so the lstm gather reads one contiguous 48B run/lane.
// ---------------------------------------------------------------------------
__global__ __launch_bounds__(256) void xgemm_split(
    const float* __restrict__ A, const float* __restrict__ B,
    const float* __restrict__ bias, _Float16* __restrict__ Chi,
    char* __restrict__ Clo)
{
    const int tid  = threadIdx.x;
    const int wave = tid >> 6, lane = tid & 63;
    const int l15  = lane & 15, quad = lane >> 4;
    const int r0   = blockIdx.y * 64 + wave * 16;
    const int c0   = blockIdx.x * 64;

    int arow = r0 + l15;
    if (arow >= NNODES) arow = NNODES - 1;

    float4_t acc[4];
#pragma unroll
    for (int ct = 0; ct < 4; ++ct) acc[ct] = (float4_t){0.f, 0.f, 0.f, 0.f};

#pragma unroll
    for (int kc = 0; kc < 4; ++kc) {
        const int kk = kc * 32 + quad * 8;
        short8_t ah, al;
        splitf8(A + (size_t)arow * 128 + kk, ah, al);
#pragma unroll
        for (int ct = 0; ct < 4; ++ct) {
            short8_t bh, bl;
            splitf8(B + (size_t)(c0 + ct * 16 + l15) * 128 + kk, bh, bl);
            acc[ct] = __builtin_amdgcn_mfma_f32_16x16x32_bf16(ah, bh, acc[ct], 0, 0, 0);
            acc[ct] = __builtin_amdgcn_mfma_f32_16x16x32_bf16(ah, bl, acc[ct], 0, 0, 0);
            acc[ct] = __builtin_amdgcn_mfma_f32_16x16x32_bf16(al, bh, acc[ct], 0, 0, 0);
        }
    }

#pragma unroll
    for (int ct = 0; ct < 4; ++ct) {
        int c = c0 + ct * 16 + l15;
        float bb = bias[c];
        const int jj = c & 127, gg = c >> 7;          // gate-interleaved slot
#pragma unroll
        for (int r = 0; r < 4; ++r) {
            int rowo = r0 + quad * 4 + r;
            if (rowo < NNODES) {
                float v = acc[ct][r] + bb;
                _Float16 hi = (_Float16)v;
                float res = v - (float)hi;
                int q = (int)rintf(res * LOSCALE);
                q = q > 127 ? 127 : (q < -127 ? -127 : q);
                Chi[(size_t)rowo * 512 + jj * 4 + gg] = hi;
                Clo[(size_t)rowo * 512 + jj * 4 + gg] = (char)q;
            }
        }
    }
}

// ---------------------------------------------------------------------------
// Fused 16-step LSTM + combine. Block = 64 nodes, 512 threads (8 waves).
// Wave w owns hidden slice j in [16w, 16w+16) for ALL 4 gates (4 tiles).
// hs in DOUBLE-BUFFERED bf16 hi/lo LDS planes -> ONE barrier per step.
// X gathers (gate-interleaved, 3x16B/lane/nt) issued at step start;
// consumed after each nt's MFMA chain (ac from zero). nbr staged in LDS.
// hs pack via v_cvt_pk_bf16_f32. NO deep pipeline: live set must stay
// under 256 regs (R10 spill lesson).
// ---------------------------------------------------------------------------
__global__ __launch_bounds__(512, 2) void lstm_comb(
    const _Float16* __restrict__ Xhi, const char* __restrict__ Xlo,
    const int* __restrict__ nbr, const float* __restrict__ Whh,
    const float* hin, const float* __restrict__ Ws,
    const float* __restrict__ Wn, const float* __restrict__ bs,
    const float* __restrict__ bn, float* hout)
{
    __shared__ short hsAhi[64 * 136], hsAlo[64 * 136];
    __shared__ short hsBhi[64 * 136], hsBlo[64 * 136];
    __shared__ int   nbrs[64 * 17];

    const int tid  = threadIdx.x;
    const int wave = tid >> 6, lane = tid & 63;
    const int l15  = lane & 15, quad = lane >> 4;
    const int n0   = blockIdx.x * 64;
    const int jb   = wave * 16;
    const int xoff = jb * 4 + quad * 16;   // gate-interleaved lane offset

    for (int i = tid; i < 64 * 136 / 2; i += 512) {
        ((unsigned*)hsAhi)[i] = 0;
        ((unsigned*)hsAlo)[i] = 0;
    }
    for (int i = tid; i < 64 * DNB; i += 512) {
        int node = n0 + (i >> 4);
        if (node >= NNODES) node = NNODES - 1;
        nbrs[(i >> 4) * 17 + (i & 15)] = nbr[node * DNB + (i & 15)];
    }

    // Whh split fragments: 4 gates x 4 k-chunks x (hi,lo) = 32 frags
    short8_t whi[4][4], wlo[4][4];
#pragma unroll
    for (int g = 0; g < 4; ++g)
#pragma unroll
        for (int kc = 0; kc < 4; ++kc)
            splitf8(Whh + (size_t)(g * 128 + jb + l15) * 128 + kc * 32 + quad * 8,
                    whi[g][kc], wlo[g][kc]);

    float cs[4][4], nh[4][4];
#pragma unroll
    for (int a = 0; a < 4; ++a)
#pragma unroll
        for (int b = 0; b < 4; ++b) { cs[a][b] = 0.f; nh[a][b] = 0.f; }

    __syncthreads();

// hi value (g,r) lives at vector slot r*4+g; lo byte g of word r.
#define XV(nt, r, g)                                                                \
    ((float)(((r) * 4 + (g)) < 8 ? xh0[nt][(r) * 4 + (g)] : xh1[nt][(r) * 4 + (g) - 8]) \
     + (float)((signed char)(xl4[nt][(r)] >> ((g) * 8))) * LOINV)

#define LSTM_STEP(rdHi, rdLo, wrHi, wrLo, T)                                        \
    {                                                                               \
        half8_t xh0[4], xh1[4]; uint4_t xl4[4];                                     \
        _Pragma("unroll")                                                           \
        for (int nt = 0; nt < 4; ++nt) {                                            \
            int gi = nbrs[(nt * 16 + l15) * 17 + (T)];                              \
            size_t xb = (size_t)gi * 512 + xoff;                                    \
            xh0[nt] = *(const half8_t*)(Xhi + xb);                                  \
            xh1[nt] = *(const half8_t*)(Xhi + xb + 8);                              \
            xl4[nt] = *(const uint4_t*)(Xlo + xb);                                  \
        }                                                                           \
        _Pragma("unroll")                                                           \
        for (int nt = 0; nt < 4; ++nt) {                                            \
            short8_t hfh[4], hfl[4];                                                \
            _Pragma("unroll")                                                       \
            for (int kc = 0; kc < 4; ++kc) {                                        \
                hfh[kc] = *(const short8_t*)&(rdHi)[(nt * 16 + l15) * 136 + kc * 32 + quad * 8]; \
                hfl[kc] = *(const short8_t*)&(rdLo)[(nt * 16 + l15) * 136 + kc * 32 + quad * 8]; \
            }                                                                       \
            float4_t ac[4];                                                         \
            _Pragma("unroll")                                                       \
            for (int g = 0; g < 4; ++g) {                                           \
                float4_t a = (float4_t){0.f, 0.f, 0.f, 0.f};                        \
                _Pragma("unroll")                                                   \
                for (int kc = 0; kc < 4; ++kc) {                                    \
                    a = __builtin_amdgcn_mfma_f32_16x16x32_bf16(whi[g][kc], hfh[kc], a, 0, 0, 0); \
                    a = __builtin_amdgcn_mfma_f32_16x16x32_bf16(whi[g][kc], hfl[kc], a, 0, 0, 0); \
                    a = __builtin_amdgcn_mfma_f32_16x16x32_bf16(wlo[g][kc], hfh[kc], a, 0, 0, 0); \
                }                                                                   \
                ac[g] = a;                                                          \
            }                                                                       \
            _Pragma("unroll")                                                       \
            for (int r = 0; r < 4; ++r) {                                           \
                float iv = ac[0][r] + XV(nt, r, 0);                                 \
                float fv = ac[1][r] + XV(nt, r, 1);                                 \
                float gv = ac[2][r] + XV(nt, r, 2);                                 \
                float ov = ac[3][r] + XV(nt, r, 3);                                 \
                float c = fsigf(fv) * cs[nt][r] + fsigf(iv) * ftanhf(gv);           \
                cs[nt][r] = c;                                                      \
                nh[nt][r] = fsigf(ov) * ftanhf(c);                                  \
            }                                                                       \
        }                                                                           \
        _Pragma("unroll")                                                           \
        for (int nt = 0; nt < 4; ++nt) {                                            \
            unsigned p0 = cvtpk(nh[nt][0], nh[nt][1]);                              \
            unsigned p1 = cvtpk(nh[nt][2], nh[nt][3]);                              \
            unsigned q0 = cvtpk(nh[nt][0] - blo(p0), nh[nt][1] - bhi(p0));          \
            unsigned q1 = cvtpk(nh[nt][2] - blo(p1), nh[nt][3] - bhi(p1));          \
            uint2 ph; ph.x = p0; ph.y = p1;                                         \
            uint2 pl; pl.x = q0; pl.y = q1;                                         \
            const int o = (nt * 16 + l15) * 136 + jb + quad * 4;                    \
            *(uint2*)&(wrHi)[o] = ph;                                               \
            *(uint2*)&(wrLo)[o] = pl;                                               \
        }                                                                           \
        __syncthreads();                                                            \
    }

    for (int tp = 0; tp < 8; ++tp) {
        LSTM_STEP(hsAhi, hsAlo, hsBhi, hsBlo, 2 * tp);      // even t: read A write B
        LSTM_STEP(hsBhi, hsBlo, hsAhi, hsAlo, 2 * tp + 1);  // odd  t: read B write A
    }
#undef LSTM_STEP
#undef XV
    // t=15 (odd) wrote A planes -> h_neigh lives in hsA.

    // ---- fused combine: h' = relu(hin@Ws.T + hn@Wn.T + bs + bn) ----
    // wave -> node group (wave&3, 16 nodes) x ct half (wave>>2, 4 tiles).
    const int ng = wave & 3, ch = wave >> 2;
    const int nodeA = n0 + ng * 16 + l15;
    const int nclA  = nodeA < NNODES ? nodeA : NNODES - 1;
    short8_t ahh[4], ahl[4], anh[4], anl[4];
#pragma unroll
    for (int kc = 0; kc < 4; ++kc) {
        splitf8(hin + (size_t)nclA * 128 + kc * 32 + quad * 8, ahh[kc], ahl[kc]);
        anh[kc] = *(const short8_t*)&hsAhi[(ng * 16 + l15) * 136 + kc * 32 + quad * 8];
        anl[kc] = *(const short8_t*)&hsAlo[(ng * 16 + l15) * 136 + kc * 32 + quad * 8];
    }
    __syncthreads();   // all hin reads done before any in-place store

#pragma unroll
    for (int ct = 0; ct < 4; ++ct) {
        const int ctg = ch * 4 + ct;
        float4_t acc = (float4_t){0.f, 0.f, 0.f, 0.f};
#pragma unroll
        for (int kc = 0; kc < 4; ++kc) {
            const int kk = kc * 32 + quad * 8;
            short8_t bh, bl;
            splitf8(Ws + (size_t)(ctg * 16 + l15) * 128 + kk, bh, bl);
            acc = __builtin_amdgcn_mfma_f32_16x16x32_bf16(ahh[kc], bh, acc, 0, 0, 0);
            acc = __builtin_amdgcn_mfma_f32_16x16x32_bf16(ahh[kc], bl, acc, 0, 0, 0);
            acc = __builtin_amdgcn_mfma_f32_16x16x32_bf16(ahl[kc], bh, acc, 0, 0, 0);
            splitf8(Wn + (size_t)(ctg * 16 + l15) * 128 + kk, bh, bl);
            acc = __builtin_amdgcn_mfma_f32_16x16x32_bf16(anh[kc], bh, acc, 0, 0, 0);
            acc = __builtin_amdgcn_mfma_f32_16x16x32_bf16(anh[kc], bl, acc, 0, 0, 0);
            acc = __builtin_amdgcn_mfma_f32_16x16x32_bf16(anl[kc], bh, acc, 0, 0, 0);
        }
        const int c = ctg * 16 + l15;
        const float bb = bs[c] + bn[c];
#pragma unroll
        for (int r = 0; r < 4; ++r) {
            int rowo = n0 + ng * 16 + quad * 4 + r;
            if (rowo < NNODES) {
                float v = acc[r] + bb;
                hout[(size_t)rowo * 128 + c] = v > 0.f ? v : 0.f;
            }
        }
    }
}

// ---------------------------------------------------------------------------
// Stacked head layer: rows [0,N) use (Bc,bc), rows [N,2N) use (Bn,bn).
// afmt=1: A fp32 N rows (both halves read same rows); afmt=0: A bf16 2N rows.
// ---------------------------------------------------------------------------
__global__ __launch_bounds__(256) void headgemm_b(
    const float* __restrict__ A32, const short* __restrict__ A16,
    const float* __restrict__ Bc, const float* __restrict__ Bn,
    const float* __restrict__ bc, const float* __restrict__ bn,
    short* __restrict__ C, int afmt)
{
    const int tid  = threadIdx.x;
    const int wave = tid >> 6, lane = tid & 63;
    const int l15  = lane & 15, quad = lane >> 4;
    const int r0   = blockIdx.x * 64 + wave * 16;
    const int c0   = blockIdx.y * 64;

    const float* Bw = (r0 < NNODES) ? Bc : Bn;
    const float* bw = (r0 < NNODES) ? bc : bn;
    int arow = r0 + l15;
    if (afmt && arow >= NNODES) arow -= NNODES;

    float4_t acc[4];
#pragma unroll
    for (int ct = 0; ct < 4; ++ct) acc[ct] = (float4_t){0.f, 0.f, 0.f, 0.f};

#pragma unroll
    for (int kc = 0; kc < 4; ++kc) {
        const int kk = kc * 32 + quad * 8;
        short8_t af = afmt ? cvtb8(A32 + (size_t)arow * 128 + kk)
                           : *(const short8_t*)(A16 + (size_t)arow * 128 + kk);
#pragma unroll
        for (int ct = 0; ct < 4; ++ct) {
            short8_t bf = cvtb8(Bw + (size_t)(c0 + ct * 16 + l15) * 128 + kk);
            acc[ct] = __builtin_amdgcn_mfma_f32_16x16x32_bf16(af, bf, acc[ct], 0, 0, 0);
        }
    }

#pragma unroll
    for (int ct = 0; ct < 4; ++ct) {
        int c = c0 + ct * 16 + l15;
        float bb = bw[c];
        float v0 = acc[ct][0] + bb; v0 = v0 > 0.f ? v0 : 0.f;
        float v1 = acc[ct][1] + bb; v1 = v1 > 0.f ? v1 : 0.f;
        float v2 = acc[ct][2] + bb; v2 = v2 > 0.f ? v2 : 0.f;
        float v3 = acc[ct][3] + bb; v3 = v3 > 0.f ? v3 : 0.f;
        unsigned p01 = cvtpk(v0, v1), p23 = cvtpk(v2, v3);
        int rb = r0 + quad * 4;
        C[(size_t)(rb + 0) * 128 + c] = (short)(p01 & 0xffff);
        C[(size_t)(rb + 1) * 128 + c] = (short)(p01 >> 16);
        C[(size_t)(rb + 2) * 128 + c] = (short)(p23 & 0xffff);
        C[(size_t)(rb + 3) * 128 + c] = (short)(p23 >> 16);
    }
}

// out[n*C+c] = x[n,:].W[c,:] + b[c]   (C = 10 or 1), bf16 acts, fp32 out.
__global__ __launch_bounds__(256) void final_b(
    const short* __restrict__ xin, const float* __restrict__ W,
    const float* __restrict__ b, float* __restrict__ out, int C)
{
    int idx = blockIdx.x * blockDim.x + threadIdx.x;
    if (idx >= NNODES * C) return;
    int n = idx / C, c = idx - n * C;
    const short* xr = xin + (size_t)n * 128;
    const float* wr = W + (size_t)c * 128;
    float acc = b[c];
#pragma unroll
    for (int i = 0; i < 16; ++i) {
        uint4 xv = *(const uint4*)(xr + i * 8);
        const float* w = wr + i * 8;
        acc += blo(xv.x) * w[0] + bhi(xv.x) * w[1]
             + blo(xv.y) * w[2] + bhi(xv.y) * w[3]
             + blo(xv.z) * w[4] + bhi(xv.z) * w[5]
             + blo(xv.w) * w[6] + bhi(xv.w) * w[7];
    }
    out[idx] = acc;
}

// ===========================================================================
extern "C" void kernel_launch(void* const* d_in, const int* in_sizes, int n_in,
                              void* d_out, int out_size, void* d_ws, size_t ws_size,
                              hipStream_t stream)
{
    const float* h0     = (const float*)d_in[0];
    const int*   nbr    = (const int*)d_in[1];
    const float* Wih    = (const float*)d_in[2];   // [2,512,128]
    const float* Whh    = (const float*)d_in[3];   // [2,512,128]
    const float* lb     = (const float*)d_in[4];   // [2,512]
    const float* Wself  = (const float*)d_in[5];   // [2,128,128]
    const float* bself  = (const float*)d_in[6];
    const float* Wneigh = (const float*)d_in[7];
    const float* bneigh = (const float*)d_in[8];
    const float* clsW   = (const float*)d_in[9];   // [5,128,128]
    const float* clsb   = (const float*)d_in[10];
    const float* clsoW  = (const float*)d_in[11];  // [10,128]
    const float* clsob  = (const float*)d_in[12];
    const float* cnfW   = (const float*)d_in[13];
    const float* cnfb   = (const float*)d_in[14];
    const float* cnfoW  = (const float*)d_in[15];  // [1,128]
    const float* cnfob  = (const float*)d_in[16];

    char* ws = (char*)d_ws;
    _Float16* Xhi = (_Float16*)ws;                 // [0, 102.4M)
    char*     Xlo = ws + 102400000;                // [102.4M, 153.6M)
    short*    actA = (short*)ws;                   // phase B: [0, 51.2M)
    short*    actB = (short*)(ws + 51200000);      // phase B: [51.2M, 102.4M)

    float* out = (float*)d_out;
    float* oC  = out;                   // [N,10]
    float* hO  = out + 1000000;         // [N,128] output 1; h1/h2 live here
    float* oL  = out + 13800000;        // [N,1]

    dim3 gx(8, 1563);    // xgemm: cols fast (L2 write-merge), M=100000, NC=512
    dim3 gl(1563);       // lstm_comb, 512 thr
    dim3 gh(3125, 2);    // heads: M=200000, NC=128, 256 thr

    // ---- layer 1: h1 -> d_out h slot ----
    xgemm_split<<<gx, dim3(256), 0, stream>>>(h0, Wih, lb, Xhi, Xlo);
    lstm_comb<<<gl, dim3(512), 0, stream>>>(Xhi, Xlo, nbr, Whh, h0,
                                            Wself, Wneigh, bself, bneigh, hO);
    // ---- layer 2: h2 -> same slot, in-place ----
    xgemm_split<<<gx, dim3(256), 0, stream>>>(hO, Wih + 65536, lb + 512, Xhi, Xlo);
    lstm_comb<<<gl, dim3(512), 0, stream>>>(Xhi, Xlo, nbr, Whh + 65536, hO,
                                            Wself + 16384, Wneigh + 16384,
                                            bself + 128, bneigh + 128, hO);

    // ---- heads: stacked cls (rows<N) / cnf (rows>=N) ----
    headgemm_b<<<gh, dim3(256), 0, stream>>>(hO, nullptr, clsW, cnfW, clsb, cnfb, actA, 1);
    short* cur = actA; short* nxt = actB;
    for (int i = 1; i < 5; ++i) {
        headgemm_b<<<gh, dim3(256), 0, stream>>>(nullptr, cur, clsW + i * 16384, cnfW + i * 16384,
                                                 clsb + i * 128, cnfb + i * 128, nxt, 0);
        short* tv = cur; cur = nxt; nxt = tv;
    }
    final_b<<<dim3((NNODES * 10 + 255) / 256), dim3(256), 0, stream>>>(cur, clsoW, clsob, oC, 10);
    final_b<<<dim3((NNODES + 255) / 256), dim3(256), 0, stream>>>(cur + (size_t)NNODES * 128,
                                                                  cnfoW, cnfob, oL, 1);
}

// Round 5
// 2919.800 us; speedup vs baseline: 1.5147x; 1.2213x over previous
//
#include <hip/hip_runtime.h>
#include <stdint.h>

// GNNCell: 2x SAGEConv(lstm) + 2 MLP heads. N=100000, D=16, H=128, fp32 I/O.
// R9  passed 3322 us (lstm 2x1175, WRITE 78MB): VALU 38.6 > MFMA 24, occ 21%
//     (2 waves/SIMD; Whh frags in AGPRs -> register-capped).
// R10 REGRESSED 4422: acA+acB pipeline -> scratch spill (WRITE 1.07GB).
// R11 partial revert still slow (lstm 1210, WRITE 168MB): inline-asm cvtpk
//     pins values to VGPRs at def -> allocator can't park Whh in AGPRs ->
//     residual spill. Lesson: NO inline asm in the register-saturated lstm.
// R12: (1) lstm_comb = byte-exact R9 restore (f2b splitf8 + f2b hs pack).
//     (2) heads: 7 dispatches (5 headgemm + 2 final_b) fused into ONE
//     persistent-tile kernel: 64-row block, activations in LDS bf16,
//     per-layer W staged global->LDS, 2 barriers/layer, both heads per
//     block. Final layers use split-bf16 compensated oW (>= old fp32
//     precision). Kills ~500MB of inter-layer activation HBM traffic.
// Precision scheme unchanged: X fp16-hi + i8-lo(2^-15), split-bf16 3-MFMA
// recurrence/X-GEMM/combine, hs bf16 hi/lo planes, heads bf16.

typedef __attribute__((ext_vector_type(8))) short short8_t;
typedef __attribute__((ext_vector_type(4))) float float4_t;
typedef __attribute__((ext_vector_type(4))) unsigned uint4_t;
typedef _Float16 half8_t __attribute__((ext_vector_type(8)));

#define NNODES 100000
#define DNB 16
#define LOSCALE 32768.0f
#define LOINV   3.0517578125e-5f   // 2^-15

__device__ __forceinline__ float fsigf(float x) {
    return __builtin_amdgcn_rcpf(1.f + __expf(-x));
}
__device__ __forceinline__ float ftanhf(float x) {
    return 1.f - 2.f * __builtin_amdgcn_rcpf(1.f + __expf(2.f * x));
}
__device__ __forceinline__ unsigned f2b(float f) {  // RNE f32->bf16 (finite)
    unsigned u = __float_as_uint(f);
    return (u + 0x7FFFu + ((u >> 16) & 1u)) >> 16;
}
__device__ __forceinline__ float blo(unsigned u) { return __uint_as_float(u << 16); }
__device__ __forceinline__ float bhi(unsigned u) { return __uint_as_float(u & 0xFFFF0000u); }
// f2b-based split: compiler-friendly (values can migrate to AGPRs).
__device__ __forceinline__ void splitf8(const float* __restrict__ p, short8_t& hi, short8_t& lo) {
    float4_t a = *(const float4_t*)p;
    float4_t b = *(const float4_t*)(p + 4);
#pragma unroll
    for (int j = 0; j < 8; ++j) {
        float x = j < 4 ? a[j] : b[j - 4];
        unsigned hb = f2b(x);
        float hf = __uint_as_float(hb << 16);
        unsigned lb = f2b(x - hf);
        hi[j] = (short)hb;
        lo[j] = (short)lb;
    }
}
// packed f32 pair -> 2x bf16 (inline asm: ONLY for transient values in
// low-pressure kernels; never in lstm_comb).
__device__ __forceinline__ unsigned cvtpk(float lo, float hi) {
    unsigned r;
    asm("v_cvt_pk_bf16_f32 %0, %1, %2" : "=v"(r) : "v"(lo), "v"(hi));
    return r;
}
__device__ __forceinline__ void splitf8_pk(const float* __restrict__ p, short8_t& hi, short8_t& lo) {
    float4_t a = *(const float4_t*)p;
    float4_t b = *(const float4_t*)(p + 4);
    unsigned h0 = cvtpk(a[0], a[1]), h1 = cvtpk(a[2], a[3]);
    unsigned h2 = cvtpk(b[0], b[1]), h3 = cvtpk(b[2], b[3]);
    unsigned l0 = cvtpk(a[0] - blo(h0), a[1] - bhi(h0));
    unsigned l1 = cvtpk(a[2] - blo(h1), a[3] - bhi(h1));
    unsigned l2 = cvtpk(b[0] - blo(h2), b[1] - bhi(h2));
    unsigned l3 = cvtpk(b[2] - blo(h3), b[3] - bhi(h3));
    union { uint4_t u; short8_t s; } ch, cl;
    ch.u = (uint4_t){h0, h1, h2, h3};
    cl.u = (uint4_t){l0, l1, l2, l3};
    hi = ch.s;
    lo = cl.s;
}
// fp32[8] -> bf16x8 (plain cast, head path)
__device__ __forceinline__ short8_t cvtb8(const float* __restrict__ p) {
    float4_t a = *(const float4_t*)p;
    float4_t b = *(const float4_t*)(p + 4);
    union { uint4_t u; short8_t s; } c;
    c.u = (uint4_t){cvtpk(a[0], a[1]), cvtpk(a[2], a[3]),
                    cvtpk(b[0], b[1]), cvtpk(b[2], b[3])};
    return c.s;
}

// ---------------------------------------------------------------------------
// X = h @ Wih.T + b, split-bf16 3-MFMA (rel ~2^-16), stored fp16-hi + i8-lo.
// GATE-INTERLEAVED output: element c = g*128+j at node*512 + j*4 + g.
// ---------------------------------------------------------------------------
__global__ __launch_bounds__(256) void xgemm_split(
    const float* __restrict__ A, const float* __restrict__ B,
    const float* __restrict__ bias, _Float16* __restrict__ Chi,
    char* __restrict__ Clo)
{
    const int tid  = threadIdx.x;
    const int wave = tid >> 6, lane = tid & 63;
    const int l15  = lane & 15, quad = lane >> 4;
    const int r0   = blockIdx.y * 64 + wave * 16;
    const int c0   = blockIdx.x * 64;

    int arow = r0 + l15;
    if (arow >= NNODES) arow = NNODES - 1;

    float4_t acc[4];
#pragma unroll
    for (int ct = 0; ct < 4; ++ct) acc[ct] = (float4_t){0.f, 0.f, 0.f, 0.f};

#pragma unroll
    for (int kc = 0; kc < 4; ++kc) {
        const int kk = kc * 32 + quad * 8;
        short8_t ah, al;
        splitf8_pk(A + (size_t)arow * 128 + kk, ah, al);
#pragma unroll
        for (int ct = 0; ct < 4; ++ct) {
            short8_t bh, bl;
            splitf8_pk(B + (size_t)(c0 + ct * 16 + l15) * 128 + kk, bh, bl);
            acc[ct] = __builtin_amdgcn_mfma_f32_16x16x32_bf16(ah, bh, acc[ct], 0, 0, 0);
            acc[ct] = __builtin_amdgcn_mfma_f32_16x16x32_bf16(ah, bl, acc[ct], 0, 0, 0);
            acc[ct] = __builtin_amdgcn_mfma_f32_16x16x32_bf16(al, bh, acc[ct], 0, 0, 0);
        }
    }

#pragma unroll
    for (int ct = 0; ct < 4; ++ct) {
        int c = c0 + ct * 16 + l15;
        float bb = bias[c];
        const int jj = c & 127, gg = c >> 7;          // gate-interleaved slot
#pragma unroll
        for (int r = 0; r < 4; ++r) {
            int rowo = r0 + quad * 4 + r;
            if (rowo < NNODES) {
                float v = acc[ct][r] + bb;
                _Float16 hi = (_Float16)v;
                float res = v - (float)hi;
                int q = (int)rintf(res * LOSCALE);
                q = q > 127 ? 127 : (q < -127 ? -127 : q);
                Chi[(size_t)rowo * 512 + jj * 4 + gg] = hi;
                Clo[(size_t)rowo * 512 + jj * 4 + gg] = (char)q;
            }
        }
    }
}

// ---------------------------------------------------------------------------
// Fused 16-step LSTM + combine — EXACT R9 code (measured 1175 us, no spill).
// Block = 64 nodes, 512 threads (8 waves); wave owns j-slice [16w,16w+16)
// for all 4 gates. hs double-buffered bf16 hi/lo LDS planes, 1 barrier/step.
// X gathers gate-interleaved 3x16B/lane/nt at step start, consumed after
// each nt's MFMA chain. nbr staged in LDS. f2b packing ONLY (AGPR-friendly).
// ---------------------------------------------------------------------------
__global__ __launch_bounds__(512, 2) void lstm_comb(
    const _Float16* __restrict__ Xhi, const char* __restrict__ Xlo,
    const int* __restrict__ nbr, const float* __restrict__ Whh,
    const float* hin, const float* __restrict__ Ws,
    const float* __restrict__ Wn, const float* __restrict__ bs,
    const float* __restrict__ bn, float* hout)
{
    __shared__ short hsAhi[64 * 136], hsAlo[64 * 136];
    __shared__ short hsBhi[64 * 136], hsBlo[64 * 136];
    __shared__ int   nbrs[64 * 17];

    const int tid  = threadIdx.x;
    const int wave = tid >> 6, lane = tid & 63;
    const int l15  = lane & 15, quad = lane >> 4;
    const int n0   = blockIdx.x * 64;
    const int jb   = wave * 16;
    const int xoff = jb * 4 + quad * 16;   // gate-interleaved lane offset

    for (int i = tid; i < 64 * 136 / 2; i += 512) {
        ((unsigned*)hsAhi)[i] = 0;
        ((unsigned*)hsAlo)[i] = 0;
    }
    for (int i = tid; i < 64 * DNB; i += 512) {
        int node = n0 + (i >> 4);
        if (node >= NNODES) node = NNODES - 1;
        nbrs[(i >> 4) * 17 + (i & 15)] = nbr[node * DNB + (i & 15)];
    }

    // Whh split fragments: 4 gates x 4 k-chunks x (hi,lo) = 32 frags
    short8_t whi[4][4], wlo[4][4];
#pragma unroll
    for (int g = 0; g < 4; ++g)
#pragma unroll
        for (int kc = 0; kc < 4; ++kc)
            splitf8(Whh + (size_t)(g * 128 + jb + l15) * 128 + kc * 32 + quad * 8,
                    whi[g][kc], wlo[g][kc]);

    float cs[4][4], nh[4][4];
#pragma unroll
    for (int a = 0; a < 4; ++a)
#pragma unroll
        for (int b = 0; b < 4; ++b) { cs[a][b] = 0.f; nh[a][b] = 0.f; }

    __syncthreads();

// hi value (g,r) lives at vector slot r*4+g; lo byte g of word r.
#define XV(nt, r, g)                                                                \
    ((float)(((r) * 4 + (g)) < 8 ? xh0[nt][(r) * 4 + (g)] : xh1[nt][(r) * 4 + (g) - 8]) \
     + (float)((signed char)(xl4[nt][(r)] >> ((g) * 8))) * LOINV)

#define LSTM_STEP(rdHi, rdLo, wrHi, wrLo, T)                                        \
    {                                                                               \
        half8_t xh0[4], xh1[4]; uint4_t xl4[4];                                     \
        _Pragma("unroll")                                                           \
        for (int nt = 0; nt < 4; ++nt) {                                            \
            int gi = nbrs[(nt * 16 + l15) * 17 + (T)];                              \
            size_t xb = (size_t)gi * 512 + xoff;                                    \
            xh0[nt] = *(const half8_t*)(Xhi + xb);                                  \
            xh1[nt] = *(const half8_t*)(Xhi + xb + 8);                              \
            xl4[nt] = *(const uint4_t*)(Xlo + xb);                                  \
        }                                                                           \
        _Pragma("unroll")                                                           \
        for (int nt = 0; nt < 4; ++nt) {                                            \
            short8_t hfh[4], hfl[4];                                                \
            _Pragma("unroll")                                                       \
            for (int kc = 0; kc < 4; ++kc) {                                        \
                hfh[kc] = *(const short8_t*)&(rdHi)[(nt * 16 + l15) * 136 + kc * 32 + quad * 8]; \
                hfl[kc] = *(const short8_t*)&(rdLo)[(nt * 16 + l15) * 136 + kc * 32 + quad * 8]; \
            }                                                                       \
            float4_t ac[4];                                                         \
            _Pragma("unroll")                                                       \
            for (int g = 0; g < 4; ++g) {                                           \
                float4_t a = (float4_t){0.f, 0.f, 0.f, 0.f};                        \
                _Pragma("unroll")                                                   \
                for (int kc = 0; kc < 4; ++kc) {                                    \
                    a = __builtin_amdgcn_mfma_f32_16x16x32_bf16(whi[g][kc], hfh[kc], a, 0, 0, 0); \
                    a = __builtin_amdgcn_mfma_f32_16x16x32_bf16(whi[g][kc], hfl[kc], a, 0, 0, 0); \
                    a = __builtin_amdgcn_mfma_f32_16x16x32_bf16(wlo[g][kc], hfh[kc], a, 0, 0, 0); \
                }                                                                   \
                ac[g] = a;                                                          \
            }                                                                       \
            _Pragma("unroll")                                                       \
            for (int r = 0; r < 4; ++r) {                                           \
                float iv = ac[0][r] + XV(nt, r, 0);                                 \
                float fv = ac[1][r] + XV(nt, r, 1);                                 \
                float gv = ac[2][r] + XV(nt, r, 2);                                 \
                float ov = ac[3][r] + XV(nt, r, 3);                                 \
                float c = fsigf(fv) * cs[nt][r] + fsigf(iv) * ftanhf(gv);           \
                cs[nt][r] = c;                                                      \
                nh[nt][r] = fsigf(ov) * ftanhf(c);                                  \
            }                                                                       \
        }                                                                           \
        _Pragma("unroll")                                                           \
        for (int nt = 0; nt < 4; ++nt) {                                            \
            unsigned hb[4], lb[4];                                                  \
            _Pragma("unroll")                                                       \
            for (int r = 0; r < 4; ++r) {                                           \
                float v = nh[nt][r];                                                \
                hb[r] = f2b(v);                                                     \
                lb[r] = f2b(v - __uint_as_float(hb[r] << 16));                      \
            }                                                                       \
            uint2 ph, pl;                                                           \
            ph.x = hb[0] | (hb[1] << 16); ph.y = hb[2] | (hb[3] << 16);             \
            pl.x = lb[0] | (lb[1] << 16); pl.y = lb[2] | (lb[3] << 16);             \
            const int o = (nt * 16 + l15) * 136 + jb + quad * 4;                    \
            *(uint2*)&(wrHi)[o] = ph;                                               \
            *(uint2*)&(wrLo)[o] = pl;                                               \
        }                                                                           \
        __syncthreads();                                                            \
    }

    for (int tp = 0; tp < 8; ++tp) {
        LSTM_STEP(hsAhi, hsAlo, hsBhi, hsBlo, 2 * tp);      // even t: read A write B
        LSTM_STEP(hsBhi, hsBlo, hsAhi, hsAlo, 2 * tp + 1);  // odd  t: read B write A
    }
#undef LSTM_STEP
#undef XV
    // t=15 (odd) wrote A planes -> h_neigh lives in hsA.

    // ---- fused combine: h' = relu(hin@Ws.T + hn@Wn.T + bs + bn) ----
    const int ng = wave & 3, ch = wave >> 2;
    const int nodeA = n0 + ng * 16 + l15;
    const int nclA  = nodeA < NNODES ? nodeA : NNODES - 1;
    short8_t ahh[4], ahl[4], anh[4], anl[4];
#pragma unroll
    for (int kc = 0; kc < 4; ++kc) {
        splitf8(hin + (size_t)nclA * 128 + kc * 32 + quad * 8, ahh[kc], ahl[kc]);
        anh[kc] = *(const short8_t*)&hsAhi[(ng * 16 + l15) * 136 + kc * 32 + quad * 8];
        anl[kc] = *(const short8_t*)&hsAlo[(ng * 16 + l15) * 136 + kc * 32 + quad * 8];
    }
    __syncthreads();   // all hin reads done before any in-place store

#pragma unroll
    for (int ct = 0; ct < 4; ++ct) {
        const int ctg = ch * 4 + ct;
        float4_t acc = (float4_t){0.f, 0.f, 0.f, 0.f};
#pragma unroll
        for (int kc = 0; kc < 4; ++kc) {
            const int kk = kc * 32 + quad * 8;
            short8_t bh, bl;
            splitf8(Ws + (size_t)(ctg * 16 + l15) * 128 + kk, bh, bl);
            acc = __builtin_amdgcn_mfma_f32_16x16x32_bf16(ahh[kc], bh, acc, 0, 0, 0);
            acc = __builtin_amdgcn_mfma_f32_16x16x32_bf16(ahh[kc], bl, acc, 0, 0, 0);
            acc = __builtin_amdgcn_mfma_f32_16x16x32_bf16(ahl[kc], bh, acc, 0, 0, 0);
            splitf8(Wn + (size_t)(ctg * 16 + l15) * 128 + kk, bh, bl);
            acc = __builtin_amdgcn_mfma_f32_16x16x32_bf16(anh[kc], bh, acc, 0, 0, 0);
            acc = __builtin_amdgcn_mfma_f32_16x16x32_bf16(anh[kc], bl, acc, 0, 0, 0);
            acc = __builtin_amdgcn_mfma_f32_16x16x32_bf16(anl[kc], bh, acc, 0, 0, 0);
        }
        const int c = ctg * 16 + l15;
        const float bb = bs[c] + bn[c];
#pragma unroll
        for (int r = 0; r < 4; ++r) {
            int rowo = n0 + ng * 16 + quad * 4 + r;
            if (rowo < NNODES) {
                float v = acc[r] + bb;
                hout[(size_t)rowo * 128 + c] = v > 0.f ? v : 0.f;
            }
        }
    }
}

// ---------------------------------------------------------------------------
// Fused MLP heads: per 64-row block, run cls (5xReLU + 10-out) and cnf
// (5xReLU + 1-out) entirely on-chip. Activations bf16 in LDS [64][132];
// per-layer W (128x128 fp32) staged global->LDS bf16 [128][132].
// 4 waves, wave owns 16 rows; per layer: 8 ct x 4 kc MFMA.
// Hidden layers bf16 W (same math as old headgemm); FINAL layers use
// split-bf16 compensated oW (2 MFMAs) >= old fp32-VALU precision.
// ---------------------------------------------------------------------------
__global__ __launch_bounds__(256) void heads_fused(
    const float* __restrict__ hsrc,
    const float* __restrict__ clsW, const float* __restrict__ clsb,
    const float* __restrict__ clsoW, const float* __restrict__ clsob,
    const float* __restrict__ cnfW, const float* __restrict__ cnfb,
    const float* __restrict__ cnfoW, const float* __restrict__ cnfob,
    float* __restrict__ oC, float* __restrict__ oL)
{
    __shared__ short xb[64 * 132];    // activations (bf16)
    __shared__ short wb[128 * 132];   // current layer weights (bf16)

    const int tid  = threadIdx.x;
    const int wave = tid >> 6, lane = tid & 63;
    const int l15  = lane & 15, quad = lane >> 4;
    const int n0   = blockIdx.x * 64;

    // h tile -> xb (bf16). thread t: row t>>2, col chunk (t&3)*32.
    {
        int row = tid >> 2, cb = (tid & 3) * 32;
        int rsrc = n0 + row; if (rsrc >= NNODES) rsrc = NNODES - 1;
        const float* src = hsrc + (size_t)rsrc * 128 + cb;
#pragma unroll
        for (int i = 0; i < 4; ++i)
            *(short8_t*)&xb[row * 132 + cb + i * 8] = cvtb8(src + i * 8);
    }

    for (int head = 0; head < 2; ++head) {
        const float* W  = head ? cnfW : clsW;
        const float* bv = head ? cnfb : clsb;

        if (head == 1) {
            __syncthreads();   // cls-final xb reads complete
            int row = tid >> 2, cb = (tid & 3) * 32;
            int rsrc = n0 + row; if (rsrc >= NNODES) rsrc = NNODES - 1;
            const float* src = hsrc + (size_t)rsrc * 128 + cb;
#pragma unroll
            for (int i = 0; i < 4; ++i)
                *(short8_t*)&xb[row * 132 + cb + i * 8] = cvtb8(src + i * 8);
        }

        for (int l = 0; l < 5; ++l) {
            __syncthreads();   // xb writes visible; prev wb consumers done
            short8_t af[4];
#pragma unroll
            for (int kc = 0; kc < 4; ++kc)
                af[kc] = *(const short8_t*)&xb[(wave * 16 + l15) * 132 + kc * 32 + quad * 8];
            // stage this layer's W: 16384 elems, 64/thread, coalesced 2KB/instr
            const float* Wl = W + (size_t)l * 16384;
#pragma unroll
            for (int i = 0; i < 8; ++i) {
                int e = i * 2048 + tid * 8;
                int r = e >> 7, c = e & 127;
                *(short8_t*)&wb[r * 132 + c] = cvtb8(Wl + e);
            }
            __syncthreads();   // wb ready; all af reads done
#pragma unroll
            for (int ct = 0; ct < 8; ++ct) {
                float4_t acc = (float4_t){0.f, 0.f, 0.f, 0.f};
#pragma unroll
                for (int kc = 0; kc < 4; ++kc) {
                    short8_t bf = *(const short8_t*)&wb[(ct * 16 + l15) * 132 + kc * 32 + quad * 8];
                    acc = __builtin_amdgcn_mfma_f32_16x16x32_bf16(af[kc], bf, acc, 0, 0, 0);
                }
                int c = ct * 16 + l15;
                float bb = bv[l * 128 + c];
#pragma unroll
                for (int r = 0; r < 4; ++r) {
                    float v = acc[r] + bb;
                    v = v > 0.f ? v : 0.f;
                    xb[(wave * 16 + quad * 4 + r) * 132 + c] = (short)f2b(v);
                }
            }
        }

        // ---- final linear (no relu), compensated split-bf16 oW ----
        __syncthreads();   // last layer xb visible
        short8_t af[4];
#pragma unroll
        for (int kc = 0; kc < 4; ++kc)
            af[kc] = *(const short8_t*)&xb[(wave * 16 + l15) * 132 + kc * 32 + quad * 8];
        if (head == 0) {
            int wr = l15 < 10 ? l15 : 9;
            float4_t acc = (float4_t){0.f, 0.f, 0.f, 0.f};
#pragma unroll
            for (int kc = 0; kc < 4; ++kc) {
                short8_t bh, bl;
                splitf8(clsoW + (size_t)wr * 128 + kc * 32 + quad * 8, bh, bl);
                acc = __builtin_amdgcn_mfma_f32_16x16x32_bf16(af[kc], bh, acc, 0, 0, 0);
                acc = __builtin_amdgcn_mfma_f32_16x16x32_bf16(af[kc], bl, acc, 0, 0, 0);
            }
            if (l15 < 10) {
                float bb = clsob[l15];
#pragma unroll
                for (int r = 0; r < 4; ++r) {
                    int row = n0 + wave * 16 + quad * 4 + r;
                    if (row < NNODES) oC[(size_t)row * 10 + l15] = acc[r] + bb;
                }
            }
        } else {
            float4_t acc = (float4_t){0.f, 0.f, 0.f, 0.f};
#pragma unroll
            for (int kc = 0; kc < 4; ++kc) {
                short8_t bh, bl;
                splitf8(cnfoW + kc * 32 + quad * 8, bh, bl);
                acc = __builtin_amdgcn_mfma_f32_16x16x32_bf16(af[kc], bh, acc, 0, 0, 0);
                acc = __builtin_amdgcn_mfma_f32_16x16x32_bf16(af[kc], bl, acc, 0, 0, 0);
            }
            if (l15 == 0) {
                float bb = cnfob[0];
#pragma unroll
                for (int r = 0; r < 4; ++r) {
                    int row = n0 + wave * 16 + quad * 4 + r;
                    if (row < NNODES) oL[row] = acc[r] + bb;
                }
            }
        }
    }
}

// ===========================================================================
extern "C" void kernel_launch(void* const* d_in, const int* in_sizes, int n_in,
                              void* d_out, int out_size, void* d_ws, size_t ws_size,
                              hipStream_t stream)
{
    const float* h0     = (const float*)d_in[0];
    const int*   nbr    = (const int*)d_in[1];
    const float* Wih    = (const float*)d_in[2];   // [2,512,128]
    const float* Whh    = (const float*)d_in[3];   // [2,512,128]
    const float* lb     = (const float*)d_in[4];   // [2,512]
    const float* Wself  = (const float*)d_in[5];   // [2,128,128]
    const float* bself  = (const float*)d_in[6];
    const float* Wneigh = (const float*)d_in[7];
    const float* bneigh = (const float*)d_in[8];
    const float* clsW   = (const float*)d_in[9];   // [5,128,128]
    const float* clsb   = (const float*)d_in[10];
    const float* clsoW  = (const float*)d_in[11];  // [10,128]
    const float* clsob  = (const float*)d_in[12];
    const float* cnfW   = (const float*)d_in[13];
    const float* cnfb   = (const float*)d_in[14];
    const float* cnfoW  = (const float*)d_in[15];  // [1,128]
    const float* cnfob  = (const float*)d_in[16];

    char* ws = (char*)d_ws;
    _Float16* Xhi = (_Float16*)ws;                 // [0, 102.4M)
    char*     Xlo = ws + 102400000;                // [102.4M, 153.6M)

    float* out = (float*)d_out;
    float* oC  = out;                   // [N,10]
    float* hO  = out + 1000000;         // [N,128] output 1; h1/h2 live here
    float* oL  = out + 13800000;        // [N,1]

    dim3 gx(8, 1563);    // xgemm: cols fast (L2 write-merge), M=100000, NC=512
    dim3 gl(1563);       // lstm_comb, 512 thr
    dim3 gf(1563);       // heads_fused, 256 thr

    // ---- layer 1: h1 -> d_out h slot ----
    xgemm_split<<<gx, dim3(256), 0, stream>>>(h0, Wih, lb, Xhi, Xlo);
    lstm_comb<<<gl, dim3(512), 0, stream>>>(Xhi, Xlo, nbr, Whh, h0,
                                            Wself, Wneigh, bself, bneigh, hO);
    // ---- layer 2: h2 -> same slot, in-place ----
    xgemm_split<<<gx, dim3(256), 0, stream>>>(hO, Wih + 65536, lb + 512, Xhi, Xlo);
    lstm_comb<<<gl, dim3(512), 0, stream>>>(Xhi, Xlo, nbr, Whh + 65536, hO,
                                            Wself + 16384, Wneigh + 16384,
                                            bself + 128, bneigh + 128, hO);

    // ---- heads: one fused dispatch ----
    heads_fused<<<gf, dim3(256), 0, stream>>>(hO, clsW, clsb, clsoW, clsob,
                                              cnfW, cnfb, cnfoW, cnfob, oC, oL);
}